// Round 1
// baseline (294.872 us; speedup 1.0000x reference)
//
#include <hip/hip_runtime.h>

#define NCLS   18
#define TROWS  256
#define TWORDS (TROWS * NCLS)              // 4608 floats per tile
#define NCHUNK ((TWORDS * 4) / 1024)       // 18 chunks of 1 KiB (64 lanes x 16 B)

#define AS1 __attribute__((address_space(1)))
#define AS3 __attribute__((address_space(3)))

__global__ __launch_bounds__(256) void ce_soft_kernel(
    const float* __restrict__ logits,
    const float* __restrict__ labels,
    float* __restrict__ result,
    int B, float invB)
{
    // 18432 B logits tile + 1 KiB lse -> 19.5 KiB LDS => 8 blocks/CU, 32 waves/CU
    __shared__ float sX[TWORDS];
    __shared__ float sLse[TROWS];

    const int tid  = threadIdx.x;
    const int lane = tid & 63;
    const int wid  = tid >> 6;

    const int nTiles = B / TROWS;          // 7812 full tiles
    float acc = 0.0f;

    for (int tile = blockIdx.x; tile < nTiles; tile += gridDim.x) {
        const float* gx = logits + (size_t)tile * TWORDS;

        // ---- coalesced global -> LDS staging: 16 B/lane, 1 KiB/wave-instr ----
        // LDS dest is wave-uniform base + lane*16 (linear layout required).
        for (int c = wid; c < NCHUNK; c += 4) {
            __builtin_amdgcn_global_load_lds(
                (const AS1 void*)(gx + c * 256 + lane * 4),
                (AS3 void*)(sX + c * 256),
                16, 0, 0);
        }
        __syncthreads();   // drains vmcnt(0) -> tile resident

        // ---- phase 1: per-row logsumexp from LDS (row tid) ----
        {
            const float2* r2 = (const float2*)(sX + tid * NCLS);  // 72B stride, 8B aligned
            float x[NCLS];
            #pragma unroll
            for (int k = 0; k < NCLS / 2; ++k) {
                float2 v = r2[k];
                x[2 * k] = v.x; x[2 * k + 1] = v.y;
            }
            float m = x[0];
            #pragma unroll
            for (int c = 1; c < NCLS; ++c) m = fmaxf(m, x[c]);
            float se = 0.0f;
            #pragma unroll
            for (int c = 0; c < NCLS; ++c) se += __expf(x[c] - m);
            sLse[tid] = m + __logf(se);
        }
        __syncthreads();

        // ---- phase 2: flat coalesced float2 pass over labels (direct global) ----
        // float2 at even word offset never spans a row boundary (18 is even).
        const float2* gl2 = (const float2*)(labels + (size_t)tile * TWORDS);
        const float2* sx2 = (const float2*)sX;
        #pragma unroll
        for (int it = 0; it < TWORDS / 512; ++it) {     // 9 iterations
            int j = it * 256 + tid;                     // float2 index in tile
            float2 lv = gl2[j];                         // coalesced: 8 B/lane
            float2 xv = sx2[j];                         // linear LDS b64
            float lse = sLse[j / 9];                    // row = (2j)/18 = j/9
            acc = fmaf(lv.x, lse - xv.x, acc);
            acc = fmaf(lv.y, lse - xv.y, acc);
        }
        __syncthreads();   // before next tile overwrites sX
    }

    // ---- tail rows (B % TROWS = 128): direct per-row path ----
    for (int row = nTiles * TROWS + blockIdx.x * blockDim.x + tid; row < B;
         row += gridDim.x * blockDim.x) {
        const float2* o2 = (const float2*)(logits + (size_t)row * NCLS);
        const float2* l2 = (const float2*)(labels + (size_t)row * NCLS);
        float x[NCLS], l[NCLS];
        #pragma unroll
        for (int k = 0; k < NCLS / 2; ++k) {
            float2 v = o2[k]; x[2 * k] = v.x; x[2 * k + 1] = v.y;
            float2 w = l2[k]; l[2 * k] = w.x; l[2 * k + 1] = w.y;
        }
        float m = x[0];
        #pragma unroll
        for (int c = 1; c < NCLS; ++c) m = fmaxf(m, x[c]);
        float se = 0.0f, dot = 0.0f, sl = 0.0f;
        #pragma unroll
        for (int c = 0; c < NCLS; ++c) {
            se += __expf(x[c] - m);
            dot = fmaf(l[c], x[c], dot);
            sl += l[c];
        }
        float lse = m + __logf(se);
        acc = fmaf(sl, lse, acc - dot);
    }

    // ---- reduction: wave shuffle -> LDS -> one atomic per block ----
    #pragma unroll
    for (int off = 32; off > 0; off >>= 1)
        acc += __shfl_down(acc, off, 64);

    __shared__ float wave_sums[4];
    if (lane == 0) wave_sums[wid] = acc;
    __syncthreads();
    if (tid == 0) {
        float s = wave_sums[0] + wave_sums[1] + wave_sums[2] + wave_sums[3];
        atomicAdd(result, s * invB);
    }
}

extern "C" void kernel_launch(void* const* d_in, const int* in_sizes, int n_in,
                              void* d_out, int out_size, void* d_ws, size_t ws_size,
                              hipStream_t stream) {
    const float* logits = (const float*)d_in[0];
    const float* labels = (const float*)d_in[1];
    float* result = (float*)d_out;

    int B = in_sizes[0] / NCLS;   // 2,000,000

    // d_out is poisoned before every launch; zero it for the atomic.
    hipMemsetAsync(d_out, 0, sizeof(float), stream);

    int block = 256;
    int grid  = 2048;             // 8 blocks/CU x 256 CU = exactly resident
    ce_soft_kernel<<<grid, block, 0, stream>>>(logits, labels, result, B, 1.0f / (float)B);
}

// Round 2
// 286.657 us; speedup vs baseline: 1.0287x; 1.0287x over previous
//
#include <hip/hip_runtime.h>

#define NCLS   18
#define TROWS  128                         // rows per tile; B = 2,000,000 = 128 * 15625 exactly
#define TWORDS (TROWS * NCLS)              // 2304 floats = 9216 B per array per tile
#define CHUNKS (TWORDS / 256)              // 9 chunks of 1 KiB (64 lanes x 16 B)

#define AS1 __attribute__((address_space(1)))
#define AS3 __attribute__((address_space(3)))

__global__ __launch_bounds__(256) void ce_soft_main(
    const float* __restrict__ logits,
    const float* __restrict__ labels,
    float* __restrict__ partial,
    int B)
{
    // 2 x (9216 logits + 9216 labels) = 36864 B LDS -> 4 blocks/CU, 16 waves/CU
    __shared__ float sX[2][TWORDS];
    __shared__ float sL[2][TWORDS];
    __shared__ float sWS[4];

    const int tid  = threadIdx.x;
    const int lane = tid & 63;
    const int wid  = tid >> 6;
    const int p    = tid >> 1;             // row pair index 0..127
    const int h    = tid & 1;              // half: owns float2-chunks (2k+h)
    const int nTiles = B / TROWS;
    const int grid = gridDim.x;

    float acc = 0.0f;
    int cur = 0;

    // ---- prologue: stage tile blockIdx into buffer 0 ----
    int t0 = blockIdx.x;
    if (t0 < nTiles) {
        const float* gx = logits + (size_t)t0 * TWORDS;
        const float* gl = labels + (size_t)t0 * TWORDS;
        for (int c = wid; c < CHUNKS; c += 4) {
            __builtin_amdgcn_global_load_lds((const AS1 void*)(gx + c * 256 + lane * 4),
                                             (AS3 void*)(&sX[0][c * 256]), 16, 0, 0);
            __builtin_amdgcn_global_load_lds((const AS1 void*)(gl + c * 256 + lane * 4),
                                             (AS3 void*)(&sL[0][c * 256]), 16, 0, 0);
        }
    }

    for (int t = t0; t < nTiles; t += grid) {
        // ONE barrier per tile: drains the stage of buf[cur] (vmcnt 0) and
        // guarantees everyone finished reading buf[cur^1] last iteration.
        __syncthreads();

        // issue next tile's stage NOW -> flies under this tile's compute
        int tn = t + grid;
        if (tn < nTiles) {
            const float* gx = logits + (size_t)tn * TWORDS;
            const float* gl = labels + (size_t)tn * TWORDS;
            float* dX = &sX[cur ^ 1][0];
            float* dL = &sL[cur ^ 1][0];
            for (int c = wid; c < CHUNKS; c += 4) {
                __builtin_amdgcn_global_load_lds((const AS1 void*)(gx + c * 256 + lane * 4),
                                                 (AS3 void*)(dX + c * 256), 16, 0, 0);
                __builtin_amdgcn_global_load_lds((const AS1 void*)(gl + c * 256 + lane * 4),
                                                 (AS3 void*)(dL + c * 256), 16, 0, 0);
            }
        }

        // ---- compute from buf[cur]: pair (2p,2p+1) shares row p ----
        const float2* rx = (const float2*)(&sX[cur][p * NCLS]);
        const float2* rl = (const float2*)(&sL[cur][p * NCLS]);
        float2 xv[5], lv[5];
        const int n = 5 - h;               // h0: chunks 0,2,4,6,8 ; h1: 1,3,5,7
        #pragma unroll
        for (int k = 0; k < 5; ++k) {
            int c = 2 * k + h;
            if (k < n) { xv[k] = rx[c];                      lv[k] = rl[c]; }
            else       { xv[k] = make_float2(-1e30f, -1e30f); lv[k] = make_float2(0.f, 0.f); }
        }
        float m = xv[0].x;
        #pragma unroll
        for (int k = 0; k < 5; ++k) { m = fmaxf(m, xv[k].x); m = fmaxf(m, xv[k].y); }
        m = fmaxf(m, __shfl_xor(m, 1, 64));          // full-row max (pair combine)
        float se = 0.f, dot = 0.f, sl = 0.f;
        #pragma unroll
        for (int k = 0; k < 5; ++k) {
            se += __expf(xv[k].x - m) + __expf(xv[k].y - m);   // dummies -> exp(-huge)=0
            dot = fmaf(lv[k].x, xv[k].x, dot);
            dot = fmaf(lv[k].y, xv[k].y, dot);
            sl += lv[k].x + lv[k].y;
        }
        se += __shfl_xor(se, 1, 64);                 // full-row sum(exp)
        float lse = m + __logf(se);
        // half-row contribution: sl_h * lse - dot_h ; halves add up correctly
        acc = fmaf(sl, lse, acc - dot);
        cur ^= 1;
    }

    // ---- generic tail (B % TROWS != 0) — empty for B = 2,000,000 ----
    for (int row = nTiles * TROWS + blockIdx.x * blockDim.x + tid; row < B;
         row += grid * blockDim.x) {
        const float2* o2 = (const float2*)(logits + (size_t)row * NCLS);
        const float2* l2 = (const float2*)(labels + (size_t)row * NCLS);
        float x[NCLS], l[NCLS];
        #pragma unroll
        for (int k = 0; k < NCLS / 2; ++k) {
            float2 v = o2[k]; x[2 * k] = v.x; x[2 * k + 1] = v.y;
            float2 w = l2[k]; l[2 * k] = w.x; l[2 * k + 1] = w.y;
        }
        float mm = x[0];
        #pragma unroll
        for (int c = 1; c < NCLS; ++c) mm = fmaxf(mm, x[c]);
        float se = 0.f, dot = 0.f, sl = 0.f;
        #pragma unroll
        for (int c = 0; c < NCLS; ++c) {
            se += __expf(x[c] - mm);
            dot = fmaf(l[c], x[c], dot);
            sl += l[c];
        }
        acc = fmaf(sl, mm + __logf(se), acc - dot);
    }

    // ---- block reduction -> plain store of partial (no atomic, no memset) ----
    #pragma unroll
    for (int off = 32; off > 0; off >>= 1)
        acc += __shfl_down(acc, off, 64);
    if (lane == 0) sWS[wid] = acc;
    __syncthreads();
    if (tid == 0)
        partial[blockIdx.x] = sWS[0] + sWS[1] + sWS[2] + sWS[3];
}

__global__ __launch_bounds__(256) void ce_soft_finish(
    const float* __restrict__ partial, float* __restrict__ result,
    int n, float invB)
{
    float s = 0.f;
    for (int i = threadIdx.x; i < n; i += 256) s += partial[i];
    #pragma unroll
    for (int off = 32; off > 0; off >>= 1)
        s += __shfl_down(s, off, 64);
    __shared__ float ws[4];
    int lane = threadIdx.x & 63, wid = threadIdx.x >> 6;
    if (lane == 0) ws[wid] = s;
    __syncthreads();
    if (threadIdx.x == 0)
        result[0] = (ws[0] + ws[1] + ws[2] + ws[3]) * invB;   // plain store overwrites poison
}

extern "C" void kernel_launch(void* const* d_in, const int* in_sizes, int n_in,
                              void* d_out, int out_size, void* d_ws, size_t ws_size,
                              hipStream_t stream) {
    const float* logits = (const float*)d_in[0];
    const float* labels = (const float*)d_in[1];
    float* result = (float*)d_out;

    int B = in_sizes[0] / NCLS;            // 2,000,000

    // grid = 1024: 4 blocks/CU (LDS-capped) x 256 CU = exactly resident
    int grid = 1024;
    size_t need = (size_t)grid * sizeof(float);
    if (ws_size < need) {                  // defensive: shrink to fit workspace
        grid = (int)(ws_size / sizeof(float));
        if (grid > 1024) grid = 1024;
        if (grid < 1) grid = 1;            // degenerate, never expected
    }
    float* partial = (float*)d_ws;

    ce_soft_main<<<grid, 256, 0, stream>>>(logits, labels, partial, B);
    ce_soft_finish<<<1, 256, 0, stream>>>(partial, result, grid, 1.0f / (float)B);
}